// Round 1
// 572.167 us; speedup vs baseline: 1.8248x; 1.8248x over previous
//
#include <hip/hip_runtime.h>
#include <stdint.h>

// ---------------------------------------------------------------------------
// FullTensorProduct: out[n,c] = sum_{a,b} x1[n,a] x2[n,b] w3j[a,b,c]
// LMAX1=LMAX2=3 -> x1,x2: [N,16], out: [N,170].
// w3j rebuilt on-device every launch (ws is re-poisoned; graph-capture-safe).
//
// v2 mapping: ONE THREAD PER ROW (64 rows/wave), contraction fully unrolled
// at compile time over the 30 path blocks. x1/x2 live in registers (static
// indices after unroll); w3j values are uniform scalar loads from a packed
// per-path table; compile-time azimuthal superset filter
// (|m3| in {|m1|+|m2|, ||m1|-|m2||} on real indices) skips guaranteed-zero
// entries. No LDS, no divergence, ~2 VALU/entry.
// ---------------------------------------------------------------------------

struct PathT { int l1, l2, l3, so; };

// Paths sorted stably by lout (replicates np.lexsort in build_w3j); so = output
// offset of each (l1,l2,lout) block within the 170-dim output.
__constant__ PathT g_paths[30] = {
    {0,0,0,0},{1,1,0,1},{2,2,0,2},{3,3,0,3},
    {0,1,1,4},{1,0,1,7},{1,2,1,10},{2,1,1,13},{2,3,1,16},{3,2,1,19},
    {0,2,2,22},{1,1,2,27},{1,3,2,32},{2,0,2,37},{2,2,2,42},{3,1,2,47},{3,3,2,52},
    {0,3,3,57},{1,2,3,64},{2,1,3,71},{2,3,3,78},{3,0,3,85},{3,2,3,92},
    {1,3,4,99},{2,2,4,108},{3,1,4,117},{3,3,4,126},
    {2,3,5,135},{3,2,5,146},
    {3,3,6,157}
};

// Packed-table base offset per path (prefix sum of D1*D2*D3).
__constant__ int g_off[30] = {
    0,1,10,35, 84,93,102,147,192,297, 402,427,472,577,602,727,832,
    1077,1126,1231,1336,1581,1630, 1875,2064,2289,2478, 2919,3304, 3689
};
// total packed entries = 4326

// Compile-time copies for the unrolled compute kernel (constexpr-foldable).
static constexpr int P_L1[30] = {0,1,2,3, 0,1,1,2,2,3, 0,1,1,2,2,3,3, 0,1,2,2,3,3, 1,2,3,3, 2,3, 3};
static constexpr int P_L2[30] = {0,1,2,3, 1,0,2,1,3,2, 2,1,3,0,2,1,3, 3,2,1,3,0,2, 3,2,1,3, 3,2, 3};
static constexpr int P_L3[30] = {0,0,0,0, 1,1,1,1,1,1, 2,2,2,2,2,2,2, 3,3,3,3,3,3, 4,4,4,4, 5,5, 6};

__constant__ double g_fact[14] = {
    1.0, 1.0, 2.0, 6.0, 24.0, 120.0, 720.0, 5040.0, 40320.0, 362880.0,
    3628800.0, 39916800.0, 479001600.0, 6227020800.0
};

struct cd { double re, im; };

__device__ __forceinline__ cd cmul(cd a, cd b) {
    return { a.re*b.re - a.im*b.im, a.re*b.im + a.im*b.re };
}

// <j1 m1 j2 m2 | j3 m3>, Racah formula. Factorial args <= 13, exact in double.
__device__ double cg_su2(int j1, int m1, int j2, int m2, int j3, int m3) {
    if (m3 != m1 + m2) return 0.0;
    double pref = sqrt((double)(2*j3+1) * g_fact[j3+j1-j2] * g_fact[j3-j1+j2]
                       * g_fact[j1+j2-j3] / g_fact[j1+j2+j3+1]);
    pref *= sqrt(g_fact[j3+m3]*g_fact[j3-m3]*g_fact[j1-m1]*g_fact[j1+m1]
                 *g_fact[j2-m2]*g_fact[j2+m2]);
    double s = 0.0;
    for (int k = 0; k <= j1+j2-j3; ++k) {
        int a = j1-m1-k, b = j2+m2-k, c = j3-j2+m1+k, d = j3-j1-m2+k;
        if (a < 0 || b < 0 || c < 0 || d < 0) continue;
        double t = 1.0 / (g_fact[k]*g_fact[j1+j2-j3-k]*g_fact[a]*g_fact[b]
                          *g_fact[c]*g_fact[d]);
        s += (k & 1) ? -t : t;
    }
    return pref * s;
}

// Entry (row,col) of real->complex change-of-basis matrix for degree l,
// including the (-i)^l phase. row = l + m_complex, col = real index.
__device__ cd qent(int l, int row, int col) {
    const double is2 = 0.70710678118654752440;
    int m = row - l;
    cd q = {0.0, 0.0};
    if (m < 0) {
        if (col == l - m)      q = { is2, 0.0 };
        else if (col == l + m) q = { 0.0, -is2 };
    } else if (m == 0) {
        if (col == l)          q = { 1.0, 0.0 };
    } else {
        double sgn = (m & 1) ? -1.0 : 1.0;
        if (col == l + m)      q = { sgn*is2, 0.0 };
        else if (col == l - m) q = { 0.0, sgn*is2 };
    }
    switch (l & 3) {                       // multiply by (-i)^l
        case 1: q = {  q.im, -q.re }; break;
        case 2: q = { -q.re, -q.im }; break;
        case 3: q = { -q.im,  q.re }; break;
        default: break;
    }
    return q;
}

// Detect input dtype: bf16 buffers have ~100% plausible bf16 exponent fields;
// f32 buffers read as u16 have ~62% (low mantissa halves are uniform bits).
__global__ void detect_dtype_kernel(const unsigned short* __restrict__ x,
                                    int n_u16_min, int* __restrict__ flag) {
    __shared__ int s[256];
    const int tid = threadIdx.x;
    int ncheck = n_u16_min < 8192 ? n_u16_min : 8192;
    int good = 0;
    for (int i = tid; i < ncheck; i += 256) {
        unsigned short v = x[i];
        int e = (v >> 7) & 0xFF;
        good += (v == 0 || (e >= 97 && e <= 158)) ? 1 : 0;
    }
    s[tid] = good;
    __syncthreads();
    for (int t = 128; t > 0; t >>= 1) {
        if (tid < t) s[tid] += s[tid + t];
        __syncthreads();
    }
    if (tid == 0) *flag = (s[0] * 10 >= ncheck * 9) ? 1 : 0;  // 1 = bf16
}

// One block per path: real-basis CG block in fp64, Frobenius-normalized,
// scaled by sqrt(2*lout+1), written into dense w3j[16][16][170].
__global__ void build_w3j_kernel(float* __restrict__ dense) {
    const int p  = blockIdx.x;
    const int l1 = g_paths[p].l1, l2 = g_paths[p].l2, l3 = g_paths[p].l3;
    const int so = g_paths[p].so;
    const int D1 = 2*l1+1, D2 = 2*l2+1, D3 = 2*l3+1;
    const int M  = D1*D2*D3;
    const int tid = threadIdx.x;

    __shared__ double sC[49];
    __shared__ double sCr[640];
    __shared__ double sred[256];

    for (int e = tid; e < D1*D2; e += blockDim.x) {
        int i = e / D2, k = e - i*D2;
        int m1 = i - l1, m2 = k - l2, m3 = m1 + m2;
        int am3 = m3 < 0 ? -m3 : m3;
        sC[e] = (am3 <= l3) ? cg_su2(l1, m1, l2, m2, l3, m3) : 0.0;
    }
    __syncthreads();

    double part = 0.0;
    for (int e = tid; e < M; e += blockDim.x) {
        int j  = e / (D2*D3);
        int r  = e - j*(D2*D3);
        int li = r / D3;
        int n  = r - li*D3;
        cd z = {0.0, 0.0};
        for (int i = 0; i < D1; ++i) {
            for (int k = 0; k < D2; ++k) {
                int m3 = (i - l1) + (k - l2);
                if (m3 < -l3 || m3 > l3) continue;
                double cval = sC[i*D2 + k];
                if (cval == 0.0) continue;
                cd q1 = qent(l1, i, j);
                if (q1.re == 0.0 && q1.im == 0.0) continue;
                cd q2 = qent(l2, k, li);
                if (q2.re == 0.0 && q2.im == 0.0) continue;
                cd q3 = qent(l3, l3 + m3, n);
                q3.im = -q3.im;  // conj
                cd t = cmul(cmul(q1, q2), q3);
                z.re += t.re * cval;
                z.im += t.im * cval;
            }
        }
        sCr[e] = z.re;
        part += z.re * z.re;
    }
    sred[tid] = part;
    __syncthreads();
    for (int s = 128; s > 0; s >>= 1) {
        if (tid < s) sred[tid] += sred[tid + s];
        __syncthreads();
    }
    const double scale = sqrt((double)(2*l3+1)) / sqrt(sred[0]);

    for (int e = tid; e < M; e += blockDim.x) {
        int j  = e / (D2*D3);
        int r  = e - j*(D2*D3);
        int li = r / D3;
        int n  = r - li*D3;
        int a = l1*l1 + j, b = l2*l2 + li, c = so + n;
        dense[(a*16 + b)*170 + c] = (float)(sCr[e] * scale);
    }
}

// Repack dense[16][16][170] into per-path contiguous layout:
// Cpk[g_off[p] + (mo*D1 + m1)*D2 + m2], so the unrolled compute kernel's
// uniform scalar loads hit consecutive addresses (s_load merging).
__global__ void repack_kernel(const float* __restrict__ dense,
                              float* __restrict__ Cpk) {
    const int p  = blockIdx.x;
    const int l1 = g_paths[p].l1, l2 = g_paths[p].l2, l3 = g_paths[p].l3;
    const int so = g_paths[p].so;
    const int D1 = 2*l1+1, D2 = 2*l2+1, D3 = 2*l3+1;
    const int M  = D1*D2*D3;
    const int base = g_off[p];
    for (int e = threadIdx.x; e < M; e += blockDim.x) {
        int mo = e / (D1*D2);
        int r  = e - mo*(D1*D2);
        int m1 = r / D2;
        int m2 = r - m1*D2;
        int a = l1*l1 + m1, b = l2*l2 + m2, c = so + mo;
        Cpk[base + e] = dense[(a*16 + b)*170 + c];
    }
}

__device__ __forceinline__ unsigned bf16_rne(float x) {
    unsigned xb = __float_as_uint(x);
    return (xb + 0x7fffu + ((xb >> 16) & 1u)) >> 16;
}

// One row per thread. Fully unrolled over the 30 paths; compile-time
// superset filter on real-basis azimuthal indices: an entry can be nonzero
// only if |m3| == |m1|+|m2| or |m3| == ||m1|-|m2||. Entries outside this set
// are exactly zero in the real CG tensor (azimuthal selection rule), so
// skipping them changes nothing numerically.
template<int MODE>
__device__ __forceinline__ void tp_row_body(const void* __restrict__ x1v,
                                            const void* __restrict__ x2v,
                                            const float* __restrict__ Cpk,
                                            void* __restrict__ outv,
                                            int row) {
    float X1[16], X2[16];

    if (MODE) {  // bf16 inputs
        const unsigned short* p1 = (const unsigned short*)x1v + (long)row*16;
        const unsigned short* p2 = (const unsigned short*)x2v + (long)row*16;
        uint4 a0 = *reinterpret_cast<const uint4*>(p1);
        uint4 a1 = *reinterpret_cast<const uint4*>(p1 + 8);
        uint4 b0 = *reinterpret_cast<const uint4*>(p2);
        uint4 b1 = *reinterpret_cast<const uint4*>(p2 + 8);
        unsigned wa[8] = {a0.x,a0.y,a0.z,a0.w,a1.x,a1.y,a1.z,a1.w};
        unsigned wb[8] = {b0.x,b0.y,b0.z,b0.w,b1.x,b1.y,b1.z,b1.w};
        #pragma unroll
        for (int i = 0; i < 8; ++i) {
            X1[2*i]   = __uint_as_float(wa[i] << 16);
            X1[2*i+1] = __uint_as_float(wa[i] & 0xFFFF0000u);
            X2[2*i]   = __uint_as_float(wb[i] << 16);
            X2[2*i+1] = __uint_as_float(wb[i] & 0xFFFF0000u);
        }
    } else {     // f32 inputs
        const float4* f1 = reinterpret_cast<const float4*>((const float*)x1v + (long)row*16);
        const float4* f2 = reinterpret_cast<const float4*>((const float*)x2v + (long)row*16);
        #pragma unroll
        for (int q = 0; q < 4; ++q) {
            float4 v1 = f1[q], v2 = f2[q];
            X1[q*4+0] = v1.x; X1[q*4+1] = v1.y; X1[q*4+2] = v1.z; X1[q*4+3] = v1.w;
            X2[q*4+0] = v2.x; X2[q*4+1] = v2.y; X2[q*4+2] = v2.z; X2[q*4+3] = v2.w;
        }
    }

    float pend = 0.0f;   // pending even-c value for paired 8B stores
    int c   = 0;
    int off = 0;

    #pragma unroll
    for (int p = 0; p < 30; ++p) {
        const int l1 = P_L1[p], l2 = P_L2[p], l3 = P_L3[p];
        const int D1 = 2*l1+1, D2 = 2*l2+1, D3 = 2*l3+1;

        #pragma unroll
        for (int mo = 0; mo < D3; ++mo) {
            const int mu3 = (mo < l3) ? (l3 - mo) : (mo - l3);
            float acc = 0.0f;
            #pragma unroll
            for (int m1 = 0; m1 < D1; ++m1) {
                const int mu1 = (m1 < l1) ? (l1 - m1) : (m1 - l1);
                float partial = 0.0f;
                int used = 0;   // constant-folds after unroll
                #pragma unroll
                for (int m2 = 0; m2 < D2; ++m2) {
                    const int mu2 = (m2 < l2) ? (l2 - m2) : (m2 - l2);
                    const int dmu = (mu1 > mu2) ? (mu1 - mu2) : (mu2 - mu1);
                    if (mu3 == mu1 + mu2 || mu3 == dmu) {
                        partial = fmaf(Cpk[off + (mo*D1 + m1)*D2 + m2],
                                       X2[l2*l2 + m2], partial);
                        used = 1;
                    }
                }
                if (used) acc = fmaf(X1[l1*l1 + m1], partial, acc);
            }

            if (c & 1) {   // flush pair {pend, acc} at even offset c-1
                if (MODE) {
                    unsigned u = bf16_rne(pend) | (bf16_rne(acc) << 16);
                    *reinterpret_cast<unsigned*>(
                        (unsigned short*)outv + (long)row*170 + (c - 1)) = u;
                } else {
                    *reinterpret_cast<float2*>(
                        (float*)outv + (long)row*170 + (c - 1)) =
                        make_float2(pend, acc);
                }
            } else {
                pend = acc;
            }
            ++c;
        }
        off += D1*D2*D3;
    }
    // 170 is even: every output was flushed by the pair logic.
}

__global__ __launch_bounds__(256)
void tp_dense_kernel(const void* __restrict__ x1v,
                     const void* __restrict__ x2v,
                     const float* __restrict__ Cpk,
                     const int*  __restrict__ flag,
                     void* __restrict__ outv,
                     int nrows) {
    const int row = blockIdx.x * blockDim.x + threadIdx.x;
    if (row >= nrows) return;
    if (*flag) tp_row_body<1>(x1v, x2v, Cpk, outv, row);
    else       tp_row_body<0>(x1v, x2v, Cpk, outv, row);
}

extern "C" void kernel_launch(void* const* d_in, const int* in_sizes, int n_in,
                              void* d_out, int out_size, void* d_ws, size_t ws_size,
                              hipStream_t stream) {
    const void* x1 = d_in[0];
    const void* x2 = d_in[1];

    char*  ws    = (char*)d_ws;
    float* dense = (float*)ws;               // 16*16*170 f32 = 174080 B
    float* Cpk   = (float*)(ws + 174080);    // 4326 f32 = 17304 B
    int*   flag  = (int*)(ws + 245824);      // 4 B (same slot as before)

    int nrows = in_sizes[0] / 16;            // 500000

    detect_dtype_kernel<<<dim3(1), dim3(256), 0, stream>>>(
        (const unsigned short*)x1, in_sizes[0], flag);
    build_w3j_kernel<<<dim3(30), dim3(256), 0, stream>>>(dense);
    repack_kernel<<<dim3(30), dim3(256), 0, stream>>>(dense, Cpk);

    int nblocks = (nrows + 255) / 256;
    tp_dense_kernel<<<dim3(nblocks), dim3(256), 0, stream>>>(
        x1, x2, Cpk, flag, d_out, nrows);
}

// Round 3
// 481.694 us; speedup vs baseline: 2.1675x; 1.1878x over previous
//
#include <hip/hip_runtime.h>
#include <stdint.h>

// ---------------------------------------------------------------------------
// FullTensorProduct: out[n,c] = sum_{a,b} x1[n,a] x2[n,b] w3j[a,b,c]
// LMAX1=LMAX2=3 -> x1,x2: [N,16], out: [N,170].
//
// v3b: identical to v3 (compile-time w3j via constexpr double math; one
// thread per row; wave-coalesced LDS-staged stores) with the constexpr
// sqrt loops iteration-capped so constant evaluation can never hit the
// clang constexpr-step limit. Previous run failed at container level with
// no diagnostic (infra flake) -> resubmit hardened.
// ---------------------------------------------------------------------------

// Path list sorted stably by lout (replicates np.lexsort in build_w3j).
constexpr int PL1c[30] = {0,1,2,3, 0,1,1,2,2,3, 0,1,1,2,2,3,3, 0,1,2,2,3,3, 1,2,3,3, 2,3, 3};
constexpr int PL2c[30] = {0,1,2,3, 1,0,2,1,3,2, 2,1,3,0,2,1,3, 3,2,1,3,0,2, 3,2,1,3, 3,2, 3};
constexpr int PL3c[30] = {0,0,0,0, 1,1,1,1,1,1, 2,2,2,2,2,2,2, 3,3,3,3,3,3, 4,4,4,4, 5,5, 6};
// Output channel offset of each path within the 170-dim output.
constexpr int SOc[30]  = {0,1,2,3, 4,7,10,13,16,19, 22,27,32,37,42,47,52,
                          57,64,71,78,85,92, 99,108,117,126, 135,146, 157};
// Packed-table base offset per path (prefix sum of D1*D2*D3; total 4326).
constexpr int OFFc[30] = {0,1,10,35, 84,93,102,147,192,297, 402,427,472,577,602,727,832,
                          1077,1126,1231,1336,1581,1630, 1875,2064,2289,2478, 2919,3304, 3689};

// ---------------- compile-time w3j builder (host constexpr) ----------------

constexpr double FACT[14] = {
    1.0, 1.0, 2.0, 6.0, 24.0, 120.0, 720.0, 5040.0, 40320.0, 362880.0,
    3628800.0, 39916800.0, 479001600.0, 6227020800.0
};

constexpr double csqrt(double x) {
    if (x <= 0.0) return 0.0;
    double y = 1.0;
    for (int i = 0; i < 600 && y * y < x; ++i)       y *= 2.0;   // seed up
    for (int i = 0; i < 600 && y * y > 4.0 * x; ++i) y *= 0.5;   // seed down
    for (int i = 0; i < 8; ++i) y = 0.5 * (y + x / y);  // Newton, quadratic
    return y;
}

struct CDc { double re, im; };

constexpr CDc cmulc(CDc a, CDc b) {
    return { a.re*b.re - a.im*b.im, a.re*b.im + a.im*b.re };
}

// <j1 m1 j2 m2 | j3 m3>, Racah formula. Factorial args <= 13, exact in double.
constexpr double cg_su2_c(int j1, int m1, int j2, int m2, int j3, int m3) {
    if (m3 != m1 + m2) return 0.0;
    double pref = csqrt((double)(2*j3+1) * FACT[j3+j1-j2] * FACT[j3-j1+j2]
                        * FACT[j1+j2-j3] / FACT[j1+j2+j3+1]);
    pref *= csqrt(FACT[j3+m3]*FACT[j3-m3]*FACT[j1-m1]*FACT[j1+m1]
                  *FACT[j2-m2]*FACT[j2+m2]);
    double s = 0.0;
    for (int k = 0; k <= j1+j2-j3; ++k) {
        int a = j1-m1-k, b = j2+m2-k, c = j3-j2+m1+k, d = j3-j1-m2+k;
        if (a < 0 || b < 0 || c < 0 || d < 0) continue;
        double t = 1.0 / (FACT[k]*FACT[j1+j2-j3-k]*FACT[a]*FACT[b]
                          *FACT[c]*FACT[d]);
        s += (k & 1) ? -t : t;
    }
    return pref * s;
}

// Entry (row,col) of real->complex change-of-basis matrix for degree l,
// including the (-i)^l phase. row = l + m_complex, col = real index.
constexpr CDc qent_c(int l, int row, int col) {
    const double is2 = 0.70710678118654752440;
    int m = row - l;
    CDc q = {0.0, 0.0};
    if (m < 0) {
        if (col == l - m)      q = { is2, 0.0 };
        else if (col == l + m) q = { 0.0, -is2 };
    } else if (m == 0) {
        if (col == l)          q = { 1.0, 0.0 };
    } else {
        double sgn = (m & 1) ? -1.0 : 1.0;
        if (col == l + m)      q = { sgn*is2, 0.0 };
        else if (col == l - m) q = { 0.0, sgn*is2 };
    }
    switch (l & 3) {                       // multiply by (-i)^l
        case 1: q = {  q.im, -q.re }; break;
        case 2: q = { -q.re, -q.im }; break;
        case 3: q = { -q.im,  q.re }; break;
        default: break;
    }
    return q;
}

struct PathDat { float coef[637]; };   // 637 = max D1*D2*D3 (path (3,3,6))

// Per-path real-basis CG block, Frobenius-normalized, * sqrt(2*l3+1).
// Q1 column j is nonzero only at rows {j, 2l1-j} (ditto Q2), so each output
// entry needs <= 4 complex terms. Each specialization is its own constant
// evaluation (stays far below clang's constexpr-step limit).
template<int P>
constexpr PathDat build_path() {
    const int l1 = PL1c[P], l2 = PL2c[P], l3 = PL3c[P];
    const int D1 = 2*l1+1, D2 = 2*l2+1, D3 = 2*l3+1;
    double cg[7][7] = {};
    for (int i = 0; i < D1; ++i)
        for (int k = 0; k < D2; ++k) {
            int m1 = i - l1, m2 = k - l2, m3 = m1 + m2;
            cg[i][k] = (m3 >= -l3 && m3 <= l3) ? cg_su2_c(l1,m1,l2,m2,l3,m3) : 0.0;
        }
    double vals[637] = {};
    double nrm = 0.0;
    for (int mo = 0; mo < D3; ++mo) {
        int mu3 = mo < l3 ? l3 - mo : mo - l3;
        for (int j = 0; j < D1; ++j) {
            int mu1 = j < l1 ? l1 - j : j - l1;
            for (int li = 0; li < D2; ++li) {
                int mu2 = li < l2 ? l2 - li : li - l2;
                int dmu = mu1 > mu2 ? mu1 - mu2 : mu2 - mu1;
                if (!(mu3 == mu1 + mu2 || mu3 == dmu)) continue;  // exact zero
                double val = 0.0;
                for (int s1 = 0; s1 < 2; ++s1) {
                    int i = s1 ? 2*l1 - j : j;
                    if (s1 && i == j) break;
                    CDc q1 = qent_c(l1, i, j);
                    if (q1.re == 0.0 && q1.im == 0.0) continue;
                    for (int s2 = 0; s2 < 2; ++s2) {
                        int k = s2 ? 2*l2 - li : li;
                        if (s2 && k == li) break;
                        int m3 = (i - l1) + (k - l2);
                        if (m3 < -l3 || m3 > l3) continue;
                        double cval = cg[i][k];
                        if (cval == 0.0) continue;
                        CDc q2 = qent_c(l2, k, li);
                        if (q2.re == 0.0 && q2.im == 0.0) continue;
                        CDc q3 = qent_c(l3, l3 + m3, mo);
                        q3.im = -q3.im;                 // conj
                        CDc t = cmulc(cmulc(q1, q2), q3);
                        val += t.re * cval;
                    }
                }
                vals[(mo*D1 + j)*D2 + li] = val;
                nrm += val * val;
            }
        }
    }
    double scale = csqrt((double)(2*l3+1)) / csqrt(nrm);
    PathDat t{};
    for (int e = 0; e < D1*D2*D3; ++e) t.coef[e] = (float)(vals[e] * scale);
    return t;
}

constexpr PathDat PD00 = build_path<0>();  constexpr PathDat PD01 = build_path<1>();
constexpr PathDat PD02 = build_path<2>();  constexpr PathDat PD03 = build_path<3>();
constexpr PathDat PD04 = build_path<4>();  constexpr PathDat PD05 = build_path<5>();
constexpr PathDat PD06 = build_path<6>();  constexpr PathDat PD07 = build_path<7>();
constexpr PathDat PD08 = build_path<8>();  constexpr PathDat PD09 = build_path<9>();
constexpr PathDat PD10 = build_path<10>(); constexpr PathDat PD11 = build_path<11>();
constexpr PathDat PD12 = build_path<12>(); constexpr PathDat PD13 = build_path<13>();
constexpr PathDat PD14 = build_path<14>(); constexpr PathDat PD15 = build_path<15>();
constexpr PathDat PD16 = build_path<16>(); constexpr PathDat PD17 = build_path<17>();
constexpr PathDat PD18 = build_path<18>(); constexpr PathDat PD19 = build_path<19>();
constexpr PathDat PD20 = build_path<20>(); constexpr PathDat PD21 = build_path<21>();
constexpr PathDat PD22 = build_path<22>(); constexpr PathDat PD23 = build_path<23>();
constexpr PathDat PD24 = build_path<24>(); constexpr PathDat PD25 = build_path<25>();
constexpr PathDat PD26 = build_path<26>(); constexpr PathDat PD27 = build_path<27>();
constexpr PathDat PD28 = build_path<28>(); constexpr PathDat PD29 = build_path<29>();

struct Flat { float c[4326]; };

constexpr Flat merge_all() {
    const PathDat* t[30] = {
        &PD00,&PD01,&PD02,&PD03,&PD04,&PD05,&PD06,&PD07,&PD08,&PD09,
        &PD10,&PD11,&PD12,&PD13,&PD14,&PD15,&PD16,&PD17,&PD18,&PD19,
        &PD20,&PD21,&PD22,&PD23,&PD24,&PD25,&PD26,&PD27,&PD28,&PD29
    };
    Flat f{};
    int o = 0;
    for (int p = 0; p < 30; ++p) {
        int M = (2*PL1c[p]+1) * (2*PL2c[p]+1) * (2*PL3c[p]+1);
        for (int e = 0; e < M; ++e) f.c[o + e] = t[p]->coef[e];
        o += M;
    }
    return f;
}

constexpr Flat FT = merge_all();   // all reads are constant-folded to literals

// ------------------------------- kernels -----------------------------------

// Detect input dtype: bf16 buffers have ~100% plausible bf16 exponent fields;
// f32 buffers read as u16 have ~62% (low mantissa halves are uniform bits).
__global__ void detect_dtype_kernel(const unsigned short* __restrict__ x,
                                    int n_u16_min, int* __restrict__ flag) {
    __shared__ int s[256];
    const int tid = threadIdx.x;
    int ncheck = n_u16_min < 8192 ? n_u16_min : 8192;
    int good = 0;
    for (int i = tid; i < ncheck; i += 256) {
        unsigned short v = x[i];
        int e = (v >> 7) & 0xFF;
        good += (v == 0 || (e >= 97 && e <= 158)) ? 1 : 0;
    }
    s[tid] = good;
    __syncthreads();
    for (int t = 128; t > 0; t >>= 1) {
        if (tid < t) s[tid] += s[tid + t];
        __syncthreads();
    }
    if (tid == 0) *flag = (s[0] * 10 >= ncheck * 9) ? 1 : 0;  // 1 = bf16
}

__device__ __forceinline__ unsigned bf16_rne(float x) {
    unsigned xb = __float_as_uint(x);
    return (xb + 0x7fffu + ((xb >> 16) & 1u)) >> 16;
}

struct alignas(8) F4 { float x, y, z, w; };

// Flush one 16-c chunk for a whole wave: lane (r0=lane>>2, p=lane&3) stores
// 16 B of row r0+16g -> full-sector transactions. Rows are 680 B apart (8 B
// aligned); gfx950 global stores need only dword alignment.
template<int MODE>
__device__ __forceinline__ void flush_chunk(float (&tile)[64][18], int lane,
                                            long rowbase, int c0,
                                            void* __restrict__ outv, int nrows) {
    const int r0 = lane >> 2, p = lane & 3;
    #pragma unroll
    for (int g = 0; g < 4; ++g) {
        const int rr = r0 + g * 16;
        const long grow = rowbase + rr;
        if (grow < nrows) {
            const float* s = &tile[rr][p * 4];
            float v0 = s[0], v1 = s[1], v2 = s[2], v3 = s[3];
            if (MODE) {
                unsigned* dst = (unsigned*)((unsigned short*)outv
                                            + grow * 170 + c0 + p * 4);
                dst[0] = bf16_rne(v0) | (bf16_rne(v1) << 16);
                dst[1] = bf16_rne(v2) | (bf16_rne(v3) << 16);
            } else {
                F4* dst = (F4*)((float*)outv + grow * 170 + c0 + p * 4);
                *dst = F4{v0, v1, v2, v3};
            }
        }
    }
}

// Tail: c = 160..169 (10 values) staged at tile[lane][0..9]; per-row flush.
template<int MODE>
__device__ __forceinline__ void flush_tail(float (&tile)[64][18], int lane,
                                           long rowbase,
                                           void* __restrict__ outv, int nrows) {
    const long grow = rowbase + lane;
    if (grow >= nrows) return;
    if (MODE) {
        unsigned short* orow = (unsigned short*)outv + grow * 170 + 160;
        #pragma unroll
        for (int j = 0; j < 5; ++j) {
            unsigned u = bf16_rne(tile[lane][2*j])
                       | (bf16_rne(tile[lane][2*j + 1]) << 16);
            *(unsigned*)(orow + 2*j) = u;
        }
    } else {
        float* orow = (float*)outv + grow * 170 + 160;
        #pragma unroll
        for (int j = 0; j < 5; ++j)
            *(float2*)(orow + 2*j) = make_float2(tile[lane][2*j],
                                                 tile[lane][2*j + 1]);
    }
}

// One row per thread. Fully unrolled over paths; every w3j coefficient is a
// compile-time literal; exact zeros pruned (folded `cf != 0` test; the
// structural azimuthal filter is kept as a guaranteed superset guard).
template<int MODE>
__device__ __forceinline__ void tp_row_body(const void* __restrict__ x1v,
                                            const void* __restrict__ x2v,
                                            void* __restrict__ outv,
                                            float (&tile)[64][18],
                                            int lane, long rowbase, int nrows) {
    const long row = rowbase + lane;
    const long rc  = row < nrows ? row : (long)nrows - 1;   // clamp for loads

    float X1[16], X2[16];
    if (MODE) {  // bf16 inputs
        const unsigned short* p1 = (const unsigned short*)x1v + rc * 16;
        const unsigned short* p2 = (const unsigned short*)x2v + rc * 16;
        uint4 a0 = *reinterpret_cast<const uint4*>(p1);
        uint4 a1 = *reinterpret_cast<const uint4*>(p1 + 8);
        uint4 b0 = *reinterpret_cast<const uint4*>(p2);
        uint4 b1 = *reinterpret_cast<const uint4*>(p2 + 8);
        unsigned wa[8] = {a0.x,a0.y,a0.z,a0.w,a1.x,a1.y,a1.z,a1.w};
        unsigned wb[8] = {b0.x,b0.y,b0.z,b0.w,b1.x,b1.y,b1.z,b1.w};
        #pragma unroll
        for (int i = 0; i < 8; ++i) {
            X1[2*i]   = __uint_as_float(wa[i] << 16);
            X1[2*i+1] = __uint_as_float(wa[i] & 0xFFFF0000u);
            X2[2*i]   = __uint_as_float(wb[i] << 16);
            X2[2*i+1] = __uint_as_float(wb[i] & 0xFFFF0000u);
        }
    } else {     // f32 inputs
        const float4* f1 = reinterpret_cast<const float4*>((const float*)x1v + rc * 16);
        const float4* f2 = reinterpret_cast<const float4*>((const float*)x2v + rc * 16);
        #pragma unroll
        for (int q = 0; q < 4; ++q) {
            float4 v1 = f1[q], v2 = f2[q];
            X1[q*4+0] = v1.x; X1[q*4+1] = v1.y; X1[q*4+2] = v1.z; X1[q*4+3] = v1.w;
            X2[q*4+0] = v2.x; X2[q*4+1] = v2.y; X2[q*4+2] = v2.z; X2[q*4+3] = v2.w;
        }
    }

    float pend = 0.0f;

    #pragma unroll
    for (int p = 0; p < 30; ++p) {
        const int l1 = PL1c[p], l2 = PL2c[p], l3 = PL3c[p];
        const int D1 = 2*l1+1, D2 = 2*l2+1, D3 = 2*l3+1;
        const int off = OFFc[p];

        #pragma unroll
        for (int mo = 0; mo < D3; ++mo) {
            const int c   = SOc[p] + mo;
            const int mu3 = (mo < l3) ? (l3 - mo) : (mo - l3);
            float acc = 0.0f;
            #pragma unroll
            for (int m1 = 0; m1 < D1; ++m1) {
                const int mu1 = (m1 < l1) ? (l1 - m1) : (m1 - l1);
                float partial = 0.0f;
                bool used = false;   // constant-folds after unroll
                #pragma unroll
                for (int m2 = 0; m2 < D2; ++m2) {
                    const int mu2 = (m2 < l2) ? (l2 - m2) : (m2 - l2);
                    const int dmu = (mu1 > mu2) ? (mu1 - mu2) : (mu2 - mu1);
                    if (mu3 == mu1 + mu2 || mu3 == dmu) {
                        const float cf = FT.c[off + (mo*D1 + m1)*D2 + m2];
                        if (cf != 0.0f) {            // folded: exact pruning
                            partial = fmaf(cf, X2[l2*l2 + m2], partial);
                            used = true;
                        }
                    }
                }
                if (used) acc = fmaf(X1[l1*l1 + m1], partial, acc);
            }

            if (c & 1) {   // stage pair {pend, acc} at chunk-local even index
                *(float2*)&tile[lane][(c - 1) & 15] = make_float2(pend, acc);
                if ((c & 15) == 15)
                    flush_chunk<MODE>(tile, lane, rowbase, c & ~15, outv, nrows);
            } else {
                pend = acc;
            }
        }
    }
    flush_tail<MODE>(tile, lane, rowbase, outv, nrows);
}

__global__ __launch_bounds__(256)
void tp_dense_kernel(const void* __restrict__ x1v,
                     const void* __restrict__ x2v,
                     const int*  __restrict__ flag,
                     void* __restrict__ outv,
                     int nrows) {
    __shared__ float stage[4][64][18];   // wave-private; stride 18: 2-way banks
    const int w    = threadIdx.x >> 6;
    const int lane = threadIdx.x & 63;
    const long rowbase = (long)blockIdx.x * 256 + w * 64;
    if (*flag) tp_row_body<1>(x1v, x2v, outv, stage[w], lane, rowbase, nrows);
    else       tp_row_body<0>(x1v, x2v, outv, stage[w], lane, rowbase, nrows);
}

extern "C" void kernel_launch(void* const* d_in, const int* in_sizes, int n_in,
                              void* d_out, int out_size, void* d_ws, size_t ws_size,
                              hipStream_t stream) {
    const void* x1 = d_in[0];
    const void* x2 = d_in[1];

    int* flag = (int*)d_ws;              // re-poisoned each call; rewritten here

    int nrows = in_sizes[0] / 16;        // 500000

    detect_dtype_kernel<<<dim3(1), dim3(256), 0, stream>>>(
        (const unsigned short*)x1, in_sizes[0], flag);

    int nblocks = (nrows + 255) / 256;
    tp_dense_kernel<<<dim3(nblocks), dim3(256), 0, stream>>>(
        x1, x2, flag, d_out, nrows);
}